// Round 1
// baseline (232.991 us; speedup 1.0000x reference)
//
#include <hip/hip_runtime.h>
#include <hip/hip_bf16.h>

// DetectionLoss: YOLO-style 3-layer loss.
// Inputs: p3 [16,3,80,80,85] f32, p4 [16,3,40,40,85] f32, p5 [16,3,20,20,85] f32,
//         boxes [16,64,4] f32 (xyxy norm), labels [16,64] i32, valid [16,64] bool,
//         anchors [3,3,2] f32. Output: scalar f32.
//
// ws layout (floats): [0..2]=npos, [3..5]=cls_sum, [6..8]=bbox_sum,
//                     [9..11]=obj_corr (sum of obj logits at unique positive cells),
//                     [12..14]=obj_bce0_sum (sum over grid of BCE(x,0))

#define NB 16
#define NM 64
#define NCLS 80
#define NCH 85

__device__ __forceinline__ float bce0(float x) {
    // BCE with target 0: max(x,0) + log1p(exp(-|x|))
    return fmaxf(x, 0.0f) + log1pf(expf(-fabsf(x)));
}

__device__ __forceinline__ float ciou_loss(float px, float py, float pw, float ph,
                                           float tx, float ty, float tw, float th) {
    float p0 = px - pw * 0.5f, p1 = py - ph * 0.5f, p2 = px + pw * 0.5f, p3 = py + ph * 0.5f;
    float t0 = tx - tw * 0.5f, t1 = ty - th * 0.5f, t2 = tx + tw * 0.5f, t3 = ty + th * 0.5f;
    float ix1 = fmaxf(p0, t0), iy1 = fmaxf(p1, t1);
    float ix2 = fminf(p2, t2), iy2 = fminf(p3, t3);
    float inter = fmaxf(ix2 - ix1, 0.0f) * fmaxf(iy2 - iy1, 0.0f);
    float a1 = (p2 - p0) * (p3 - p1);
    float a2 = (t2 - t0) * (t3 - t1);
    float iou = inter / (a1 + a2 - inter + 1e-7f);
    float pcx = (p0 + p2) * 0.5f, pcy = (p1 + p3) * 0.5f;
    float tcx = (t0 + t2) * 0.5f, tcy = (t1 + t3) * 0.5f;
    float cd = (pcx - tcx) * (pcx - tcx) + (pcy - tcy) * (pcy - tcy);
    float ex1 = fminf(p0, t0), ey1 = fminf(p1, t1);
    float ex2 = fmaxf(p2, t2), ey2 = fmaxf(p3, t3);
    float dd = (ex2 - ex1) * (ex2 - ex1) + (ey2 - ey1) * (ey2 - ey1);
    return 1.0f - (iou - cd / (dd + 1e-7f));
}

// Kernel A: per-box work. One block of 1024 threads (one per (b,m)).
__global__ __launch_bounds__(1024) void kA(
    const float* __restrict__ p3, const float* __restrict__ p4, const float* __restrict__ p5,
    const float* __restrict__ boxes, const int* __restrict__ labels,
    const unsigned char* __restrict__ validb, const float* __restrict__ anchors,
    float* __restrict__ ws)
{
    __shared__ int s_info[3][1024];     // packed: pos<<16 | a<<14 | gy<<7 | gx
    __shared__ int s_recIdx[3072];
    __shared__ int s_recMeta[3072];     // label | layer<<16
    __shared__ float s_acc[12];         // npos[3], cls[3], bbox[3], corr[3]
    __shared__ int s_nrec;
    __shared__ int s_nz[4];
    __shared__ int s_flag;

    const int t = threadIdx.x;
    if (t < 12) s_acc[t] = 0.0f;
    if (t == 0) s_nrec = 0;
    if (t < 4) s_nz[t] = 0;
    __syncthreads();

    // --- detect 'valid' storage layout from byte patterns of first 1024 bytes ---
    if (t < 256) {
        int nz = 0;
#pragma unroll
        for (int j = 0; j < 4; j++) if (validb[t * 4 + j]) nz |= (1 << j);
        if (nz & 1) atomicOr(&s_nz[0], 1);
        if (nz & 2) atomicOr(&s_nz[1], 1);
        if (nz & 4) atomicOr(&s_nz[2], 1);
        if (nz & 8) atomicOr(&s_nz[3], 1);
    }
    __syncthreads();
    if (t == 0) {
        int f;
        if (!s_nz[1] && !s_nz[2] && !s_nz[3]) f = 0;      // int32 0/1 (only low byte ever set)
        else if (!s_nz[0] && !s_nz[1]) f = 2;             // float32 1.0f (bytes 00 00 80 3f)
        else f = 1;                                        // uint8 bool
        s_flag = f;
    }
    __syncthreads();
    const int flag = s_flag;

    const int b = t >> 6;
    const int m = t & 63;
    const float x1 = boxes[t * 4 + 0], y1 = boxes[t * 4 + 1];
    const float x2 = boxes[t * 4 + 2], y2 = boxes[t * 4 + 3];
    bool valid;
    if (flag == 0)      valid = ((const int*)validb)[t] != 0;
    else if (flag == 1) valid = validb[t] != 0;
    else                valid = ((const float*)validb)[t] != 0.0f;
    const int label = labels[t];

    const int GDIM[3] = {80, 40, 20};
    float cxl[3], cyl[3], wl[3], hl[3];
    int infol[3];
#pragma unroll
    for (int l = 0; l < 3; l++) {
        const float g = (float)GDIM[l];
        const float cx = (x1 + x2) * 0.5f * g;
        const float cy = (y1 + y2) * 0.5f * g;
        const float w = (x2 - x1) * g;
        const float h = (y2 - y1) * g;
        float best = -1.0f; int ba = 0;
#pragma unroll
        for (int a = 0; a < 3; a++) {
            const float aw = anchors[l * 6 + a * 2 + 0];
            const float ah = anchors[l * 6 + a * 2 + 1];
            const float inter = fminf(w, aw) * fminf(h, ah);
            const float uni = w * h + aw * ah - inter;
            const float iou = inter / (uni + 1e-6f);
            if (iou > best) { best = iou; ba = a; }   // first-max tie-break like jnp.argmax
        }
        const bool pos = valid && (best > 0.5f);
        int gx = (int)cx; gx = gx < 0 ? 0 : (gx > GDIM[l] - 1 ? GDIM[l] - 1 : gx);
        int gy = (int)cy; gy = gy < 0 ? 0 : (gy > GDIM[l] - 1 ? GDIM[l] - 1 : gy);
        const int info = (pos ? (1 << 16) : 0) | (ba << 14) | (gy << 7) | gx;
        s_info[l][t] = info;
        infol[l] = info; cxl[l] = cx; cyl[l] = cy; wl[l] = w; hl[l] = h;
    }
    __syncthreads();

#pragma unroll
    for (int l = 0; l < 3; l++) {
        const int info = infol[l];
        if (info & (1 << 16)) {
            const int ba = (info >> 14) & 3, gy = (info >> 7) & 127, gx = info & 127;
            const int g = GDIM[l];
            const int idx = (((b * 3 + ba) * g + gy) * g + gx) * NCH;
            const float* base = (l == 0) ? p3 : ((l == 1) ? p4 : p5);
            atomicAdd(&s_acc[l], 1.0f);  // npos
            const float bb = ciou_loss(base[idx + 0], base[idx + 1], base[idx + 2], base[idx + 3],
                                       cxl[l], cyl[l], wl[l], hl[l]);
            atomicAdd(&s_acc[6 + l], bb);
            // dedupe: only the lowest-m box owning this cell contributes the obj correction
            bool dup = false;
            const int rowbase = b * 64;
            for (int mm = 0; mm < m; mm++) {
                if (s_info[l][rowbase + mm] == info) { dup = true; break; }
            }
            if (!dup) atomicAdd(&s_acc[9 + l], base[idx + 4]);
            const int r = atomicAdd(&s_nrec, 1);
            s_recIdx[r] = idx;
            s_recMeta[r] = label | (l << 16);
        }
    }
    __syncthreads();

    // cls BCE over (record, class) jobs
    const int P = s_nrec;
    float acc0 = 0.0f, acc1 = 0.0f, acc2 = 0.0f;
    const int total = P * NCLS;
    for (int job = t; job < total; job += 1024) {
        const int r = job / NCLS;
        const int c = job - r * NCLS;
        const int idx = s_recIdx[r];
        const int meta = s_recMeta[r];
        const int l = meta >> 16;
        const int lab = meta & 0xFFFF;
        const float* base = (l == 0) ? p3 : ((l == 1) ? p4 : p5);
        const float logit = base[idx + 5 + c];
        const float tv = (c == lab) ? 1.0f : 0.0f;
        const float bce = fmaxf(logit, 0.0f) - logit * tv + log1pf(expf(-fabsf(logit)));
        acc0 += (l == 0) ? bce : 0.0f;
        acc1 += (l == 1) ? bce : 0.0f;
        acc2 += (l == 2) ? bce : 0.0f;
    }
#pragma unroll
    for (int off = 32; off > 0; off >>= 1) {
        acc0 += __shfl_down(acc0, off);
        acc1 += __shfl_down(acc1, off);
        acc2 += __shfl_down(acc2, off);
    }
    if ((t & 63) == 0) {
        atomicAdd(&s_acc[3], acc0);
        atomicAdd(&s_acc[4], acc1);
        atomicAdd(&s_acc[5], acc2);
    }
    __syncthreads();

    if (t < 12) ws[t] = s_acc[t];
    if (t >= 12 && t < 15) ws[t] = 0.0f;   // zero obj sums for kernel B
}

// Kernel B: sum of BCE(x,0) over obj channel of each layer's full grid.
__global__ __launch_bounds__(256) void kB(
    const float* __restrict__ p3, const float* __restrict__ p4, const float* __restrict__ p5,
    float* __restrict__ ws)
{
    const int blk = blockIdx.x, t = threadIdx.x;
    int layer, cell0, ncell;
    const float* base;
    if (blk < 300)      { layer = 0; cell0 = blk * 1024;         ncell = 307200; base = p3; }
    else if (blk < 375) { layer = 1; cell0 = (blk - 300) * 1024; ncell = 76800;  base = p4; }
    else                { layer = 2; cell0 = (blk - 375) * 1024; ncell = 19200;  base = p5; }
    float acc = 0.0f;
#pragma unroll
    for (int k = 0; k < 4; k++) {
        const int cell = cell0 + k * 256 + t;
        if (cell < ncell) {
            const float x = base[(size_t)cell * NCH + 4];
            acc += bce0(x);
        }
    }
#pragma unroll
    for (int off = 32; off > 0; off >>= 1) acc += __shfl_down(acc, off);
    __shared__ float s[4];
    if ((t & 63) == 0) s[t >> 6] = acc;
    __syncthreads();
    if (t == 0) atomicAdd(&ws[12 + layer], s[0] + s[1] + s[2] + s[3]);
}

// Kernel C: final combine.
__global__ void kC(const float* __restrict__ ws, float* __restrict__ out) {
    float cls = 0.0f, obj = 0.0f, box = 0.0f;
    const float GRID[3] = {307200.0f, 76800.0f, 19200.0f};
    for (int l = 0; l < 3; l++) {
        const float npos = ws[l];
        const float has = npos > 0.0f ? 1.0f : 0.0f;
        const float denom = fmaxf(npos, 1.0f);
        cls += has * ws[3 + l] / (denom * 80.0f);
        box += has * ws[6 + l] / denom;
        obj += has * (ws[12 + l] - ws[9 + l]) / GRID[l];
    }
    out[0] = 0.5f * cls + 1.0f * obj + 0.05f * box;
}

extern "C" void kernel_launch(void* const* d_in, const int* in_sizes, int n_in,
                              void* d_out, int out_size, void* d_ws, size_t ws_size,
                              hipStream_t stream) {
    const float* p3 = (const float*)d_in[0];
    const float* p4 = (const float*)d_in[1];
    const float* p5 = (const float*)d_in[2];
    const float* boxes = (const float*)d_in[3];
    const int* labels = (const int*)d_in[4];
    const unsigned char* validb = (const unsigned char*)d_in[5];
    const float* anchors = (const float*)d_in[6];
    float* ws = (float*)d_ws;
    float* out = (float*)d_out;

    kA<<<1, 1024, 0, stream>>>(p3, p4, p5, boxes, labels, validb, anchors, ws);
    kB<<<394, 256, 0, stream>>>(p3, p4, p5, ws);
    kC<<<1, 1, 0, stream>>>(ws, out);
}